// Round 1
// baseline (2663.510 us; speedup 1.0000x reference)
//
#include <hip/hip_runtime.h>

#define D 128
#define TR 64
#define BK 32

static __device__ __forceinline__ float4 f4add(float4 a, float4 b) {
    return make_float4(a.x + b.x, a.y + b.y, a.z + b.z, a.w + b.w);
}

// ---------------- Kernel 1: fused edge aggregation ----------------
// agg_n[dst] += nfeat[src];  agg_e[dst] += efeat[e];  deg[dst] += 1
__global__ void k_edge_agg(const float* __restrict__ nfeat,
                           const float* __restrict__ efeat,
                           const int* __restrict__ src,
                           const int* __restrict__ dst,
                           float* __restrict__ agg_n,
                           float* __restrict__ agg_e,
                           float* __restrict__ deg,
                           int E)
{
    const int tid  = blockIdx.x * blockDim.x + threadIdx.x;
    const int lane = tid & 63;
    const int wid  = tid >> 6;
    const int nw   = (gridDim.x * blockDim.x) >> 6;
    const float2* nf2 = (const float2*)nfeat;
    const float2* ef2 = (const float2*)efeat;
    for (int e = wid; e < E; e += nw) {
        const int s = src[e];
        const int d = dst[e];
        const float2 nv = nf2[s * 64 + lane];
        const float2 ev = ef2[e * 64 + lane];
        float* an = agg_n + d * D + lane * 2;
        float* ae = agg_e + d * D + lane * 2;
        atomicAdd(an + 0, nv.x);
        atomicAdd(an + 1, nv.y);
        atomicAdd(ae + 0, ev.x);
        atomicAdd(ae + 1, ev.y);
        if (lane == 0) atomicAdd(deg + d, 1.0f);
    }
}

// ---------------- Kernel 2: h1 = (nfeat+agg_n)@W1 + b1, + BN partial sums ----
#define FMA_ROW(i, xv)                                                         \
    acc[i][0] += xv * w0.x; acc[i][1] += xv * w0.y;                            \
    acc[i][2] += xv * w0.z; acc[i][3] += xv * w0.w;                            \
    acc[i][4] += xv * w1.x; acc[i][5] += xv * w1.y;                            \
    acc[i][6] += xv * w1.z; acc[i][7] += xv * w1.w;

__global__ __launch_bounds__(256) void k_h1(const float* __restrict__ nfeat,
                                            const float* __restrict__ agg_n,
                                            const float* __restrict__ W1,
                                            const float* __restrict__ b1,
                                            float* __restrict__ h1,
                                            float* __restrict__ stats,
                                            int N)
{
    __shared__ float xs[TR * 132];   // 64 rows, padded stride 132
    __shared__ float wsh[BK * 128];  // W chunk
    const int t = threadIdx.x;
    const int row0 = blockIdx.x * TR;

    // stage x tile = nfeat + agg_n
    for (int i = t; i < TR * 32; i += 256) {
        const int r = i >> 5, c4 = i & 31;
        const int row = row0 + r;
        float4 v = make_float4(0.f, 0.f, 0.f, 0.f);
        if (row < N) {
            const float4 a = *(const float4*)(nfeat + row * D + c4 * 4);
            const float4 g = *(const float4*)(agg_n + row * D + c4 * 4);
            v = f4add(a, g);
        }
        *(float4*)(xs + r * 132 + c4 * 4) = v;
    }

    float acc[4][8];
    #pragma unroll
    for (int i = 0; i < 4; ++i)
        #pragma unroll
        for (int j = 0; j < 8; ++j) acc[i][j] = 0.f;

    const int rg = (t >> 4) * 4;  // first of 4 rows owned
    const int c  = t & 15;        // float4 col chunk (cols 4c..4c+3 and 64+4c..)

    for (int kc = 0; kc < D; kc += BK) {
        __syncthreads();
        #pragma unroll
        for (int i = 0; i < 4; ++i) {
            const int slot = i * 256 + t;
            const int k = slot >> 5, ch = slot & 31;
            *(float4*)(wsh + k * 128 + ch * 4) =
                *(const float4*)(W1 + (kc + k) * D + ch * 4);
        }
        __syncthreads();
        #pragma unroll 8
        for (int k = 0; k < BK; ++k) {
            const float4 w0 = *(const float4*)(wsh + k * 128 + c * 4);
            const float4 w1 = *(const float4*)(wsh + k * 128 + 64 + c * 4);
            const float x0 = xs[(rg + 0) * 132 + kc + k];
            const float x1 = xs[(rg + 1) * 132 + kc + k];
            const float x2 = xs[(rg + 2) * 132 + kc + k];
            const float x3 = xs[(rg + 3) * 132 + kc + k];
            FMA_ROW(0, x0)
            FMA_ROW(1, x1)
            FMA_ROW(2, x2)
            FMA_ROW(3, x3)
        }
    }

    const float4 bb0 = *(const float4*)(b1 + c * 4);
    const float4 bb1 = *(const float4*)(b1 + 64 + c * 4);
    float cs[8], cq[8];
    #pragma unroll
    for (int j = 0; j < 8; ++j) { cs[j] = 0.f; cq[j] = 0.f; }

    #pragma unroll
    for (int i = 0; i < 4; ++i) {
        const int row = row0 + rg + i;
        if (row < N) {
            float h[8];
            h[0] = acc[i][0] + bb0.x; h[1] = acc[i][1] + bb0.y;
            h[2] = acc[i][2] + bb0.z; h[3] = acc[i][3] + bb0.w;
            h[4] = acc[i][4] + bb1.x; h[5] = acc[i][5] + bb1.y;
            h[6] = acc[i][6] + bb1.z; h[7] = acc[i][7] + bb1.w;
            *(float4*)(h1 + row * D + c * 4)      = make_float4(h[0], h[1], h[2], h[3]);
            *(float4*)(h1 + row * D + 64 + c * 4) = make_float4(h[4], h[5], h[6], h[7]);
            #pragma unroll
            for (int j = 0; j < 8; ++j) { cs[j] += h[j]; cq[j] += h[j] * h[j]; }
        }
    }
    #pragma unroll
    for (int j = 0; j < 4; ++j) {
        atomicAdd(stats + c * 4 + j,            cs[j]);
        atomicAdd(stats + 128 + c * 4 + j,      cq[j]);
        atomicAdd(stats + 64 + c * 4 + j,       cs[4 + j]);
        atomicAdd(stats + 128 + 64 + c * 4 + j, cq[4 + j]);
    }
}

// ---------------- Kernel 3: finalize BN stats into (scale, shift) ----------
__global__ void k_bn_finalize(float* __restrict__ stats,
                              const float* __restrict__ gamma,
                              const float* __restrict__ beta,
                              int N)
{
    const int c = threadIdx.x;
    const float invN = 1.0f / (float)N;
    const float sum = stats[c];
    const float sq  = stats[D + c];
    const float mu  = sum * invN;
    const float var = sq * invN - mu * mu;
    const float sc  = gamma[c] * rsqrtf(var + 1e-5f);
    const float sh  = beta[c] - mu * sc;
    stats[c]     = sc;
    stats[D + c] = sh;
}

// ---------------- Kernel 4: out = relu(bn(h1))@W2 + agg_e@We + b2 + deg*be --
__global__ __launch_bounds__(256) void k_out(const float* __restrict__ h1,
                                             const float* __restrict__ agg_e,
                                             const float* __restrict__ stats,
                                             const float* __restrict__ W2,
                                             const float* __restrict__ b2,
                                             const float* __restrict__ We,
                                             const float* __restrict__ be,
                                             const float* __restrict__ deg,
                                             float* __restrict__ out,
                                             int N)
{
    __shared__ float xs[TR * 132];
    __shared__ float wsh[BK * 128];
    const int t = threadIdx.x;
    const int row0 = blockIdx.x * TR;
    const int rg = (t >> 4) * 4;
    const int c  = t & 15;

    float acc[4][8];
    #pragma unroll
    for (int i = 0; i < 4; ++i)
        #pragma unroll
        for (int j = 0; j < 8; ++j) acc[i][j] = 0.f;

    // ---- phase A: relu(bn(h1)) @ W2 ----
    for (int i = t; i < TR * 32; i += 256) {
        const int r = i >> 5, c4 = i & 31;
        const int row = row0 + r;
        float4 v = make_float4(0.f, 0.f, 0.f, 0.f);
        if (row < N) {
            const float4 h  = *(const float4*)(h1 + row * D + c4 * 4);
            const float4 sc = *(const float4*)(stats + c4 * 4);
            const float4 sh = *(const float4*)(stats + 128 + c4 * 4);
            v.x = fmaxf(h.x * sc.x + sh.x, 0.f);
            v.y = fmaxf(h.y * sc.y + sh.y, 0.f);
            v.z = fmaxf(h.z * sc.z + sh.z, 0.f);
            v.w = fmaxf(h.w * sc.w + sh.w, 0.f);
        }
        *(float4*)(xs + r * 132 + c4 * 4) = v;
    }
    for (int kc = 0; kc < D; kc += BK) {
        __syncthreads();
        #pragma unroll
        for (int i = 0; i < 4; ++i) {
            const int slot = i * 256 + t;
            const int k = slot >> 5, ch = slot & 31;
            *(float4*)(wsh + k * 128 + ch * 4) =
                *(const float4*)(W2 + (kc + k) * D + ch * 4);
        }
        __syncthreads();
        #pragma unroll 8
        for (int k = 0; k < BK; ++k) {
            const float4 w0 = *(const float4*)(wsh + k * 128 + c * 4);
            const float4 w1 = *(const float4*)(wsh + k * 128 + 64 + c * 4);
            const float x0 = xs[(rg + 0) * 132 + kc + k];
            const float x1 = xs[(rg + 1) * 132 + kc + k];
            const float x2 = xs[(rg + 2) * 132 + kc + k];
            const float x3 = xs[(rg + 3) * 132 + kc + k];
            FMA_ROW(0, x0)
            FMA_ROW(1, x1)
            FMA_ROW(2, x2)
            FMA_ROW(3, x3)
        }
    }
    __syncthreads();

    // ---- phase B: agg_e @ We ----
    for (int i = t; i < TR * 32; i += 256) {
        const int r = i >> 5, c4 = i & 31;
        const int row = row0 + r;
        float4 v = make_float4(0.f, 0.f, 0.f, 0.f);
        if (row < N) v = *(const float4*)(agg_e + row * D + c4 * 4);
        *(float4*)(xs + r * 132 + c4 * 4) = v;
    }
    for (int kc = 0; kc < D; kc += BK) {
        __syncthreads();
        #pragma unroll
        for (int i = 0; i < 4; ++i) {
            const int slot = i * 256 + t;
            const int k = slot >> 5, ch = slot & 31;
            *(float4*)(wsh + k * 128 + ch * 4) =
                *(const float4*)(We + (kc + k) * D + ch * 4);
        }
        __syncthreads();
        #pragma unroll 8
        for (int k = 0; k < BK; ++k) {
            const float4 w0 = *(const float4*)(wsh + k * 128 + c * 4);
            const float4 w1 = *(const float4*)(wsh + k * 128 + 64 + c * 4);
            const float x0 = xs[(rg + 0) * 132 + kc + k];
            const float x1 = xs[(rg + 1) * 132 + kc + k];
            const float x2 = xs[(rg + 2) * 132 + kc + k];
            const float x3 = xs[(rg + 3) * 132 + kc + k];
            FMA_ROW(0, x0)
            FMA_ROW(1, x1)
            FMA_ROW(2, x2)
            FMA_ROW(3, x3)
        }
    }

    // ---- epilogue ----
    const float4 b20 = *(const float4*)(b2 + c * 4);
    const float4 b21 = *(const float4*)(b2 + 64 + c * 4);
    const float4 be0 = *(const float4*)(be + c * 4);
    const float4 be1 = *(const float4*)(be + 64 + c * 4);
    #pragma unroll
    for (int i = 0; i < 4; ++i) {
        const int row = row0 + rg + i;
        if (row < N) {
            const float dg = deg[row];
            const float4 o0 = make_float4(acc[i][0] + b20.x + dg * be0.x,
                                          acc[i][1] + b20.y + dg * be0.y,
                                          acc[i][2] + b20.z + dg * be0.z,
                                          acc[i][3] + b20.w + dg * be0.w);
            const float4 o1 = make_float4(acc[i][4] + b21.x + dg * be1.x,
                                          acc[i][5] + b21.y + dg * be1.y,
                                          acc[i][6] + b21.z + dg * be1.z,
                                          acc[i][7] + b21.w + dg * be1.w);
            *(float4*)(out + row * D + c * 4)      = o0;
            *(float4*)(out + row * D + 64 + c * 4) = o1;
        }
    }
}

extern "C" void kernel_launch(void* const* d_in, const int* in_sizes, int n_in,
                              void* d_out, int out_size, void* d_ws, size_t ws_size,
                              hipStream_t stream) {
    const float* nfeat = (const float*)d_in[0];
    const float* efeat = (const float*)d_in[1];
    const int*   src   = (const int*)d_in[2];
    const int*   dst   = (const int*)d_in[3];
    const float* W1    = (const float*)d_in[4];
    const float* b1    = (const float*)d_in[5];
    const float* gamma = (const float*)d_in[6];
    const float* beta  = (const float*)d_in[7];
    const float* W2    = (const float*)d_in[8];
    const float* b2    = (const float*)d_in[9];
    const float* We    = (const float*)d_in[10];
    const float* be    = (const float*)d_in[11];
    float* out = (float*)d_out;

    const int N = in_sizes[0] / D;
    const int E = in_sizes[2];

    float* ws    = (float*)d_ws;
    float* agg_n = ws;
    float* agg_e = ws + (size_t)N * D;
    float* h1    = ws + (size_t)2 * N * D;
    float* deg   = ws + (size_t)3 * N * D;
    float* stats = deg + N;

    // zero the accumulated regions every call (harness does not re-poison)
    hipMemsetAsync(agg_n, 0, (size_t)2 * N * D * sizeof(float), stream);
    hipMemsetAsync(deg, 0, (size_t)(N + 256) * sizeof(float), stream);

    k_edge_agg<<<2048, 256, 0, stream>>>(nfeat, efeat, src, dst, agg_n, agg_e, deg, E);

    const int nb = (N + TR - 1) / TR;
    k_h1<<<nb, 256, 0, stream>>>(nfeat, agg_n, W1, b1, h1, stats, N);
    k_bn_finalize<<<1, 128, 0, stream>>>(stats, gamma, beta, N);
    k_out<<<nb, 256, 0, stream>>>(h1, agg_e, stats, W2, b2, We, be, deg, out, N);
}

// Round 2
// 345.779 us; speedup vs baseline: 7.7029x; 7.7029x over previous
//
#include <hip/hip_runtime.h>

#define D 128
#define TR 64
#define BK 32

static __device__ __forceinline__ float4 f4add(float4 a, float4 b) {
    return make_float4(a.x + b.x, a.y + b.y, a.z + b.z, a.w + b.w);
}

// ================= CSR build =================

__global__ void k_hist(const int* __restrict__ dst, int* __restrict__ cnt, int E) {
    const int e = blockIdx.x * 256 + threadIdx.x;
    if (e < E) atomicAdd(&cnt[dst[e]], 1);
}

// chunk = 1024 per block, 256 threads x 4 elements
__global__ __launch_bounds__(256) void k_scan1(const int* __restrict__ cnt,
                                               int* __restrict__ row_ptr,
                                               int* __restrict__ bsum, int N) {
    __shared__ int sh[256];
    const int t = threadIdx.x;
    const int base = blockIdx.x * 1024 + t * 4;
    int4 v = make_int4(0, 0, 0, 0);
    if (base + 3 < N) v = *(const int4*)(cnt + base);
    else {
        if (base     < N) v.x = cnt[base];
        if (base + 1 < N) v.y = cnt[base + 1];
        if (base + 2 < N) v.z = cnt[base + 2];
        if (base + 3 < N) v.w = cnt[base + 3];
    }
    const int s = v.x + v.y + v.z + v.w;
    sh[t] = s;
    __syncthreads();
    for (int off = 1; off < 256; off <<= 1) {
        int tmp = (t >= off) ? sh[t - off] : 0;
        __syncthreads();
        sh[t] += tmp;
        __syncthreads();
    }
    const int p = sh[t] - s;  // exclusive prefix of this thread's 4-group
    if (base     < N) row_ptr[base]     = p;
    if (base + 1 < N) row_ptr[base + 1] = p + v.x;
    if (base + 2 < N) row_ptr[base + 2] = p + v.x + v.y;
    if (base + 3 < N) row_ptr[base + 3] = p + v.x + v.y + v.z;
    if (t == 255) bsum[blockIdx.x] = sh[255];
}

__global__ __launch_bounds__(256) void k_scan2(int* __restrict__ bsum, int nb) {
    __shared__ int sh[256];
    const int t = threadIdx.x;
    const int v = (t < nb) ? bsum[t] : 0;
    sh[t] = v;
    __syncthreads();
    for (int off = 1; off < 256; off <<= 1) {
        int tmp = (t >= off) ? sh[t - off] : 0;
        __syncthreads();
        sh[t] += tmp;
        __syncthreads();
    }
    if (t < nb) bsum[t] = sh[t] - v;  // exclusive
}

__global__ __launch_bounds__(256) void k_scan3(int* __restrict__ row_ptr,
                                               int* __restrict__ cursor,
                                               const int* __restrict__ bsum,
                                               int N, int E) {
    const int t = threadIdx.x;
    const int base = blockIdx.x * 1024 + t * 4;
    const int off = bsum[blockIdx.x];
    #pragma unroll
    for (int j = 0; j < 4; ++j) {
        const int i = base + j;
        if (i < N) {
            const int r = row_ptr[i] + off;
            row_ptr[i] = r;
            cursor[i] = r;
        }
    }
    if (blockIdx.x == 0 && t == 0) row_ptr[N] = E;
}

__global__ void k_scatter(const int* __restrict__ src, const int* __restrict__ dst,
                          int* __restrict__ cursor,
                          int* __restrict__ eidx, int* __restrict__ esrc, int E) {
    const int e = blockIdx.x * 256 + threadIdx.x;
    if (e < E) {
        const int d = dst[e];
        const int p = atomicAdd(&cursor[d], 1);
        eidx[p] = e;
        esrc[p] = src[e];
    }
}

// ================= gather aggregation: one wave per node =================
__global__ __launch_bounds__(256) void k_gather(const float* __restrict__ nfeat,
                                                const float* __restrict__ efeat,
                                                const int* __restrict__ row_ptr,
                                                const int* __restrict__ eidx,
                                                const int* __restrict__ esrc,
                                                float* __restrict__ agg_n,
                                                float* __restrict__ agg_e,
                                                int N) {
    const int t = threadIdx.x;
    const int lane = t & 63;
    const int node = blockIdx.x * 4 + (t >> 6);
    if (node >= N) return;
    const float2* nf2 = (const float2*)nfeat;
    const float2* ef2 = (const float2*)efeat;
    const int start = row_ptr[node];
    const int end = row_ptr[node + 1];
    float2 an = make_float2(0.f, 0.f);
    float2 ae = make_float2(0.f, 0.f);
    int i = start;
    for (; i + 1 < end; i += 2) {
        const int e0 = eidx[i],     s0 = esrc[i];
        const int e1 = eidx[i + 1], s1 = esrc[i + 1];
        const float2 ev0 = ef2[(size_t)e0 * 64 + lane];
        const float2 nv0 = nf2[(size_t)s0 * 64 + lane];
        const float2 ev1 = ef2[(size_t)e1 * 64 + lane];
        const float2 nv1 = nf2[(size_t)s1 * 64 + lane];
        ae.x += ev0.x + ev1.x; ae.y += ev0.y + ev1.y;
        an.x += nv0.x + nv1.x; an.y += nv0.y + nv1.y;
    }
    if (i < end) {
        const int e0 = eidx[i], s0 = esrc[i];
        const float2 ev0 = ef2[(size_t)e0 * 64 + lane];
        const float2 nv0 = nf2[(size_t)s0 * 64 + lane];
        ae.x += ev0.x; ae.y += ev0.y;
        an.x += nv0.x; an.y += nv0.y;
    }
    ((float2*)agg_n)[(size_t)node * 64 + lane] = an;
    ((float2*)agg_e)[(size_t)node * 64 + lane] = ae;
}

// ================= matmuls =================
#define FMA_ROW(i, xv)                                                         \
    acc[i][0] += xv * w0.x; acc[i][1] += xv * w0.y;                            \
    acc[i][2] += xv * w0.z; acc[i][3] += xv * w0.w;                            \
    acc[i][4] += xv * w1.x; acc[i][5] += xv * w1.y;                            \
    acc[i][6] += xv * w1.z; acc[i][7] += xv * w1.w;

__global__ __launch_bounds__(256) void k_h1(const float* __restrict__ nfeat,
                                            const float* __restrict__ agg_n,
                                            const float* __restrict__ W1,
                                            const float* __restrict__ b1,
                                            float* __restrict__ h1,
                                            float* __restrict__ stats,
                                            int N) {
    __shared__ float xs[TR * 132];
    __shared__ float wsh[BK * 128];  // 4096 floats, reused as reduction buffer
    const int t = threadIdx.x;
    const int row0 = blockIdx.x * TR;

    for (int i = t; i < TR * 32; i += 256) {
        const int r = i >> 5, c4 = i & 31;
        const int row = row0 + r;
        float4 v = make_float4(0.f, 0.f, 0.f, 0.f);
        if (row < N) {
            const float4 a = *(const float4*)(nfeat + row * D + c4 * 4);
            const float4 g = *(const float4*)(agg_n + row * D + c4 * 4);
            v = f4add(a, g);
        }
        *(float4*)(xs + r * 132 + c4 * 4) = v;
    }

    float acc[4][8];
    #pragma unroll
    for (int i = 0; i < 4; ++i)
        #pragma unroll
        for (int j = 0; j < 8; ++j) acc[i][j] = 0.f;

    const int rg = (t >> 4) * 4;
    const int c  = t & 15;

    for (int kc = 0; kc < D; kc += BK) {
        __syncthreads();
        #pragma unroll
        for (int i = 0; i < 4; ++i) {
            const int slot = i * 256 + t;
            const int k = slot >> 5, ch = slot & 31;
            *(float4*)(wsh + k * 128 + ch * 4) =
                *(const float4*)(W1 + (kc + k) * D + ch * 4);
        }
        __syncthreads();
        #pragma unroll 8
        for (int k = 0; k < BK; ++k) {
            const float4 w0 = *(const float4*)(wsh + k * 128 + c * 4);
            const float4 w1 = *(const float4*)(wsh + k * 128 + 64 + c * 4);
            const float x0 = xs[(rg + 0) * 132 + kc + k];
            const float x1 = xs[(rg + 1) * 132 + kc + k];
            const float x2 = xs[(rg + 2) * 132 + kc + k];
            const float x3 = xs[(rg + 3) * 132 + kc + k];
            FMA_ROW(0, x0)
            FMA_ROW(1, x1)
            FMA_ROW(2, x2)
            FMA_ROW(3, x3)
        }
    }

    const float4 bb0 = *(const float4*)(b1 + c * 4);
    const float4 bb1 = *(const float4*)(b1 + 64 + c * 4);
    float cs[8], cq[8];
    #pragma unroll
    for (int j = 0; j < 8; ++j) { cs[j] = 0.f; cq[j] = 0.f; }

    #pragma unroll
    for (int i = 0; i < 4; ++i) {
        const int row = row0 + rg + i;
        if (row < N) {
            float h[8];
            h[0] = acc[i][0] + bb0.x; h[1] = acc[i][1] + bb0.y;
            h[2] = acc[i][2] + bb0.z; h[3] = acc[i][3] + bb0.w;
            h[4] = acc[i][4] + bb1.x; h[5] = acc[i][5] + bb1.y;
            h[6] = acc[i][6] + bb1.z; h[7] = acc[i][7] + bb1.w;
            *(float4*)(h1 + row * D + c * 4)      = make_float4(h[0], h[1], h[2], h[3]);
            *(float4*)(h1 + row * D + 64 + c * 4) = make_float4(h[4], h[5], h[6], h[7]);
            #pragma unroll
            for (int j = 0; j < 8; ++j) { cs[j] += h[j]; cq[j] += h[j] * h[j]; }
        }
    }

    // block-level LDS reduction of BN partial sums, then 1 atomic per slot
    __syncthreads();                 // everyone done with wsh
    float* red = wsh;                // 16 groups x 256 slots
    const int g = t >> 4;
    #pragma unroll
    for (int j = 0; j < 4; ++j) {
        red[g * 256 +       4 * c + j] = cs[j];
        red[g * 256 +  64 + 4 * c + j] = cs[4 + j];
        red[g * 256 + 128 + 4 * c + j] = cq[j];
        red[g * 256 + 192 + 4 * c + j] = cq[4 + j];
    }
    __syncthreads();
    float v = 0.f;
    #pragma unroll
    for (int g2 = 0; g2 < 16; ++g2) v += red[g2 * 256 + t];
    atomicAdd(stats + t, v);
}

__global__ void k_bn_finalize(float* __restrict__ stats,
                              const float* __restrict__ gamma,
                              const float* __restrict__ beta,
                              int N) {
    const int c = threadIdx.x;
    const float invN = 1.0f / (float)N;
    const float sum = stats[c];
    const float sq  = stats[D + c];
    const float mu  = sum * invN;
    const float var = sq * invN - mu * mu;
    const float sc  = gamma[c] * rsqrtf(var + 1e-5f);
    const float sh  = beta[c] - mu * sc;
    stats[c]     = sc;
    stats[D + c] = sh;
}

__global__ __launch_bounds__(256) void k_out(const float* __restrict__ h1,
                                             const float* __restrict__ agg_e,
                                             const float* __restrict__ stats,
                                             const float* __restrict__ W2,
                                             const float* __restrict__ b2,
                                             const float* __restrict__ We,
                                             const float* __restrict__ be,
                                             const int* __restrict__ row_ptr,
                                             float* __restrict__ out,
                                             int N) {
    __shared__ float xs[TR * 132];
    __shared__ float wsh[BK * 128];
    const int t = threadIdx.x;
    const int row0 = blockIdx.x * TR;
    const int rg = (t >> 4) * 4;
    const int c  = t & 15;

    float acc[4][8];
    #pragma unroll
    for (int i = 0; i < 4; ++i)
        #pragma unroll
        for (int j = 0; j < 8; ++j) acc[i][j] = 0.f;

    // ---- phase A: relu(bn(h1)) @ W2 ----
    for (int i = t; i < TR * 32; i += 256) {
        const int r = i >> 5, c4 = i & 31;
        const int row = row0 + r;
        float4 v = make_float4(0.f, 0.f, 0.f, 0.f);
        if (row < N) {
            const float4 h  = *(const float4*)(h1 + row * D + c4 * 4);
            const float4 sc = *(const float4*)(stats + c4 * 4);
            const float4 sh = *(const float4*)(stats + 128 + c4 * 4);
            v.x = fmaxf(h.x * sc.x + sh.x, 0.f);
            v.y = fmaxf(h.y * sc.y + sh.y, 0.f);
            v.z = fmaxf(h.z * sc.z + sh.z, 0.f);
            v.w = fmaxf(h.w * sc.w + sh.w, 0.f);
        }
        *(float4*)(xs + r * 132 + c4 * 4) = v;
    }
    for (int kc = 0; kc < D; kc += BK) {
        __syncthreads();
        #pragma unroll
        for (int i = 0; i < 4; ++i) {
            const int slot = i * 256 + t;
            const int k = slot >> 5, ch = slot & 31;
            *(float4*)(wsh + k * 128 + ch * 4) =
                *(const float4*)(W2 + (kc + k) * D + ch * 4);
        }
        __syncthreads();
        #pragma unroll 8
        for (int k = 0; k < BK; ++k) {
            const float4 w0 = *(const float4*)(wsh + k * 128 + c * 4);
            const float4 w1 = *(const float4*)(wsh + k * 128 + 64 + c * 4);
            const float x0 = xs[(rg + 0) * 132 + kc + k];
            const float x1 = xs[(rg + 1) * 132 + kc + k];
            const float x2 = xs[(rg + 2) * 132 + kc + k];
            const float x3 = xs[(rg + 3) * 132 + kc + k];
            FMA_ROW(0, x0)
            FMA_ROW(1, x1)
            FMA_ROW(2, x2)
            FMA_ROW(3, x3)
        }
    }
    __syncthreads();

    // ---- phase B: agg_e @ We ----
    for (int i = t; i < TR * 32; i += 256) {
        const int r = i >> 5, c4 = i & 31;
        const int row = row0 + r;
        float4 v = make_float4(0.f, 0.f, 0.f, 0.f);
        if (row < N) v = *(const float4*)(agg_e + row * D + c4 * 4);
        *(float4*)(xs + r * 132 + c4 * 4) = v;
    }
    for (int kc = 0; kc < D; kc += BK) {
        __syncthreads();
        #pragma unroll
        for (int i = 0; i < 4; ++i) {
            const int slot = i * 256 + t;
            const int k = slot >> 5, ch = slot & 31;
            *(float4*)(wsh + k * 128 + ch * 4) =
                *(const float4*)(We + (kc + k) * D + ch * 4);
        }
        __syncthreads();
        #pragma unroll 8
        for (int k = 0; k < BK; ++k) {
            const float4 w0 = *(const float4*)(wsh + k * 128 + c * 4);
            const float4 w1 = *(const float4*)(wsh + k * 128 + 64 + c * 4);
            const float x0 = xs[(rg + 0) * 132 + kc + k];
            const float x1 = xs[(rg + 1) * 132 + kc + k];
            const float x2 = xs[(rg + 2) * 132 + kc + k];
            const float x3 = xs[(rg + 3) * 132 + kc + k];
            FMA_ROW(0, x0)
            FMA_ROW(1, x1)
            FMA_ROW(2, x2)
            FMA_ROW(3, x3)
        }
    }

    const float4 b20 = *(const float4*)(b2 + c * 4);
    const float4 b21 = *(const float4*)(b2 + 64 + c * 4);
    const float4 be0 = *(const float4*)(be + c * 4);
    const float4 be1 = *(const float4*)(be + 64 + c * 4);
    #pragma unroll
    for (int i = 0; i < 4; ++i) {
        const int row = row0 + rg + i;
        if (row < N) {
            const float dg = (float)(row_ptr[row + 1] - row_ptr[row]);
            const float4 o0 = make_float4(acc[i][0] + b20.x + dg * be0.x,
                                          acc[i][1] + b20.y + dg * be0.y,
                                          acc[i][2] + b20.z + dg * be0.z,
                                          acc[i][3] + b20.w + dg * be0.w);
            const float4 o1 = make_float4(acc[i][4] + b21.x + dg * be1.x,
                                          acc[i][5] + b21.y + dg * be1.y,
                                          acc[i][6] + b21.z + dg * be1.z,
                                          acc[i][7] + b21.w + dg * be1.w);
            *(float4*)(out + row * D + c * 4)      = o0;
            *(float4*)(out + row * D + 64 + c * 4) = o1;
        }
    }
}

extern "C" void kernel_launch(void* const* d_in, const int* in_sizes, int n_in,
                              void* d_out, int out_size, void* d_ws, size_t ws_size,
                              hipStream_t stream) {
    const float* nfeat = (const float*)d_in[0];
    const float* efeat = (const float*)d_in[1];
    const int*   src   = (const int*)d_in[2];
    const int*   dst   = (const int*)d_in[3];
    const float* W1    = (const float*)d_in[4];
    const float* b1    = (const float*)d_in[5];
    const float* gamma = (const float*)d_in[6];
    const float* beta  = (const float*)d_in[7];
    const float* W2    = (const float*)d_in[8];
    const float* b2    = (const float*)d_in[9];
    const float* We    = (const float*)d_in[10];
    const float* be    = (const float*)d_in[11];
    float* out = (float*)d_out;

    const int N = in_sizes[0] / D;
    const int E = in_sizes[2];

    // workspace layout (h1 aliases agg_n: k_h1 stages its rows before writing them)
    float* ws      = (float*)d_ws;
    float* agg_n   = ws;                         // N*D
    float* h1      = agg_n;                      // aliased
    float* agg_e   = ws + (size_t)N * D;         // N*D
    float* stats   = ws + (size_t)2 * N * D;     // 256
    int*   row_ptr = (int*)(stats + 256);        // N+16
    int*   cursor  = row_ptr + (N + 16);         // N+16
    int*   cnt     = cursor + (N + 16);          // N+16
    int*   bsum    = cnt + (N + 16);             // 64
    int*   eidx    = bsum + 64;                  // E
    int*   esrc    = eidx + E;                   // E

    hipMemsetAsync(cnt, 0, (size_t)N * sizeof(int), stream);
    hipMemsetAsync(stats, 0, 256 * sizeof(float), stream);

    const int ebl = (E + 255) / 256;
    const int scb = (N + 1023) / 1024;

    k_hist<<<ebl, 256, 0, stream>>>(dst, cnt, E);
    k_scan1<<<scb, 256, 0, stream>>>(cnt, row_ptr, bsum, N);
    k_scan2<<<1, 256, 0, stream>>>(bsum, scb);
    k_scan3<<<scb, 256, 0, stream>>>(row_ptr, cursor, bsum, N, E);
    k_scatter<<<ebl, 256, 0, stream>>>(src, dst, cursor, eidx, esrc, E);

    k_gather<<<(N + 3) / 4, 256, 0, stream>>>(nfeat, efeat, row_ptr, eidx, esrc,
                                              agg_n, agg_e, N);

    const int nb = (N + TR - 1) / TR;
    k_h1<<<nb, 256, 0, stream>>>(nfeat, agg_n, W1, b1, h1, stats, N);
    k_bn_finalize<<<1, 128, 0, stream>>>(stats, gamma, beta, N);
    k_out<<<nb, 256, 0, stream>>>(h1, agg_e, stats, W2, b2, We, be, row_ptr, out, N);
}

// Round 3
// 333.733 us; speedup vs baseline: 7.9810x; 1.0361x over previous
//
#include <hip/hip_runtime.h>

#define D 128
#define TR 64
#define BK 32

static __device__ __forceinline__ float4 f4add(float4 a, float4 b) {
    return make_float4(a.x + b.x, a.y + b.y, a.z + b.z, a.w + b.w);
}

// ================= zero scratch (replaces in-graph hipMemsetAsync) =========
__global__ void k_zero(int* __restrict__ cnt, float* __restrict__ stats, int N) {
    const int i = blockIdx.x * 256 + threadIdx.x;
    if (i < N) cnt[i] = 0;
    if (i < 256) stats[i] = 0.f;
}

// ================= CSR build =================
__global__ void k_hist(const int* __restrict__ dst, int* __restrict__ cnt, int E) {
    const int base = (blockIdx.x * 256 + threadIdx.x) * 4;
    if (base + 3 < E) {
        const int4 d4 = *(const int4*)(dst + base);
        atomicAdd(&cnt[d4.x], 1);
        atomicAdd(&cnt[d4.y], 1);
        atomicAdd(&cnt[d4.z], 1);
        atomicAdd(&cnt[d4.w], 1);
    } else {
        for (int e = base; e < E; ++e) atomicAdd(&cnt[dst[e]], 1);
    }
}

// chunk = 1024 per block, 256 threads x 4 elements
__global__ __launch_bounds__(256) void k_scan1(const int* __restrict__ cnt,
                                               int* __restrict__ row_ptr,
                                               int* __restrict__ bsum, int N) {
    __shared__ int sh[256];
    const int t = threadIdx.x;
    const int base = blockIdx.x * 1024 + t * 4;
    int4 v = make_int4(0, 0, 0, 0);
    if (base + 3 < N) v = *(const int4*)(cnt + base);
    else {
        if (base     < N) v.x = cnt[base];
        if (base + 1 < N) v.y = cnt[base + 1];
        if (base + 2 < N) v.z = cnt[base + 2];
        if (base + 3 < N) v.w = cnt[base + 3];
    }
    const int s = v.x + v.y + v.z + v.w;
    sh[t] = s;
    __syncthreads();
    for (int off = 1; off < 256; off <<= 1) {
        int tmp = (t >= off) ? sh[t - off] : 0;
        __syncthreads();
        sh[t] += tmp;
        __syncthreads();
    }
    const int p = sh[t] - s;
    if (base     < N) row_ptr[base]     = p;
    if (base + 1 < N) row_ptr[base + 1] = p + v.x;
    if (base + 2 < N) row_ptr[base + 2] = p + v.x + v.y;
    if (base + 3 < N) row_ptr[base + 3] = p + v.x + v.y + v.z;
    if (t == 255) bsum[blockIdx.x] = sh[255];
}

__global__ __launch_bounds__(256) void k_scan2(int* __restrict__ bsum, int nb) {
    __shared__ int sh[256];
    const int t = threadIdx.x;
    const int v = (t < nb) ? bsum[t] : 0;
    sh[t] = v;
    __syncthreads();
    for (int off = 1; off < 256; off <<= 1) {
        int tmp = (t >= off) ? sh[t - off] : 0;
        __syncthreads();
        sh[t] += tmp;
        __syncthreads();
    }
    if (t < nb) bsum[t] = sh[t] - v;
}

__global__ __launch_bounds__(256) void k_scan3(int* __restrict__ row_ptr,
                                               int* __restrict__ cursor,
                                               const int* __restrict__ bsum,
                                               int N, int E) {
    const int t = threadIdx.x;
    const int base = blockIdx.x * 1024 + t * 4;
    const int off = bsum[blockIdx.x];
    #pragma unroll
    for (int j = 0; j < 4; ++j) {
        const int i = base + j;
        if (i < N) {
            const int r = row_ptr[i] + off;
            row_ptr[i] = r;
            cursor[i] = r;
        }
    }
    if (blockIdx.x == 0 && t == 0) row_ptr[N] = E;
}

__global__ void k_scatter(const int* __restrict__ src, const int* __restrict__ dst,
                          int* __restrict__ cursor,
                          int2* __restrict__ epair, int E) {
    const int base = (blockIdx.x * 256 + threadIdx.x) * 4;
    if (base + 3 < E) {
        const int4 d4 = *(const int4*)(dst + base);
        const int4 s4 = *(const int4*)(src + base);
        int p;
        p = atomicAdd(&cursor[d4.x], 1); epair[p] = make_int2(base + 0, s4.x);
        p = atomicAdd(&cursor[d4.y], 1); epair[p] = make_int2(base + 1, s4.y);
        p = atomicAdd(&cursor[d4.z], 1); epair[p] = make_int2(base + 2, s4.z);
        p = atomicAdd(&cursor[d4.w], 1); epair[p] = make_int2(base + 3, s4.w);
    } else {
        for (int e = base; e < E; ++e) {
            const int p = atomicAdd(&cursor[dst[e]], 1);
            epair[p] = make_int2(e, src[e]);
        }
    }
}

// ================= gather: one wave per node, 2 edges per iteration ========
// writes x = nfeat[node] + sum nfeat[src], and agg_e = sum efeat[e]
__global__ __launch_bounds__(256) void k_gather(const float* __restrict__ nfeat,
                                                const float* __restrict__ efeat,
                                                const int* __restrict__ row_ptr,
                                                const int2* __restrict__ epair,
                                                float* __restrict__ xbuf,
                                                float* __restrict__ agg_e,
                                                int N) {
    const int t = threadIdx.x;
    const int lane = t & 63;
    const int h = lane >> 5;      // half-wave id: handles edges start+h, +2, ...
    const int c = lane & 31;      // float4 chunk within the 128-dim row
    const int node = blockIdx.x * 4 + (t >> 6);
    if (node >= N) return;

    const int start = row_ptr[node];
    const int end   = row_ptr[node + 1];

    float4 an = make_float4(0.f, 0.f, 0.f, 0.f);
    float4 ae = make_float4(0.f, 0.f, 0.f, 0.f);
    for (int e = start + h; e < end; e += 2) {
        const int2 p = epair[e];
        const float4 ev = *(const float4*)(efeat + (size_t)p.x * D + c * 4);
        const float4 nv = *(const float4*)(nfeat + (size_t)p.y * D + c * 4);
        ae = f4add(ae, ev);
        an = f4add(an, nv);
    }
    // combine the two halves
    float4 an_t, ae_t;
    an_t.x = an.x + __shfl_xor(an.x, 32);
    an_t.y = an.y + __shfl_xor(an.y, 32);
    an_t.z = an.z + __shfl_xor(an.z, 32);
    an_t.w = an.w + __shfl_xor(an.w, 32);
    ae_t.x = ae.x + __shfl_xor(ae.x, 32);
    ae_t.y = ae.y + __shfl_xor(ae.y, 32);
    ae_t.z = ae.z + __shfl_xor(ae.z, 32);
    ae_t.w = ae.w + __shfl_xor(ae.w, 32);

    if (h == 0) {
        const float4 self = *(const float4*)(nfeat + (size_t)node * D + c * 4);
        *(float4*)(xbuf  + (size_t)node * D + c * 4) = f4add(self, an_t);
        *(float4*)(agg_e + (size_t)node * D + c * 4) = ae_t;
    }
}

// ================= matmuls =================
#define FMA_ROW(i, xv)                                                         \
    acc[i][0] += xv * w0.x; acc[i][1] += xv * w0.y;                            \
    acc[i][2] += xv * w0.z; acc[i][3] += xv * w0.w;                            \
    acc[i][4] += xv * w1.x; acc[i][5] += xv * w1.y;                            \
    acc[i][6] += xv * w1.z; acc[i][7] += xv * w1.w;

__global__ __launch_bounds__(256) void k_h1(const float* __restrict__ xbuf,
                                            const float* __restrict__ W1,
                                            const float* __restrict__ b1,
                                            float* __restrict__ h1,
                                            float* __restrict__ stats,
                                            int N) {
    __shared__ float xs[TR * 132];
    __shared__ float wsh[BK * 128];  // reused as reduction buffer at the end
    const int t = threadIdx.x;
    const int row0 = blockIdx.x * TR;

    for (int i = t; i < TR * 32; i += 256) {
        const int r = i >> 5, c4 = i & 31;
        const int row = row0 + r;
        float4 v = make_float4(0.f, 0.f, 0.f, 0.f);
        if (row < N) v = *(const float4*)(xbuf + (size_t)row * D + c4 * 4);
        *(float4*)(xs + r * 132 + c4 * 4) = v;
    }

    float acc[4][8];
    #pragma unroll
    for (int i = 0; i < 4; ++i)
        #pragma unroll
        for (int j = 0; j < 8; ++j) acc[i][j] = 0.f;

    const int rg = (t >> 4) * 4;
    const int c  = t & 15;

    for (int kc = 0; kc < D; kc += BK) {
        __syncthreads();
        #pragma unroll
        for (int i = 0; i < 4; ++i) {
            const int slot = i * 256 + t;
            const int k = slot >> 5, ch = slot & 31;
            *(float4*)(wsh + k * 128 + ch * 4) =
                *(const float4*)(W1 + (kc + k) * D + ch * 4);
        }
        __syncthreads();
        #pragma unroll 8
        for (int k = 0; k < BK; ++k) {
            const float4 w0 = *(const float4*)(wsh + k * 128 + c * 4);
            const float4 w1 = *(const float4*)(wsh + k * 128 + 64 + c * 4);
            const float x0 = xs[(rg + 0) * 132 + kc + k];
            const float x1 = xs[(rg + 1) * 132 + kc + k];
            const float x2 = xs[(rg + 2) * 132 + kc + k];
            const float x3 = xs[(rg + 3) * 132 + kc + k];
            FMA_ROW(0, x0)
            FMA_ROW(1, x1)
            FMA_ROW(2, x2)
            FMA_ROW(3, x3)
        }
    }

    const float4 bb0 = *(const float4*)(b1 + c * 4);
    const float4 bb1 = *(const float4*)(b1 + 64 + c * 4);
    float cs[8], cq[8];
    #pragma unroll
    for (int j = 0; j < 8; ++j) { cs[j] = 0.f; cq[j] = 0.f; }

    #pragma unroll
    for (int i = 0; i < 4; ++i) {
        const int row = row0 + rg + i;
        if (row < N) {
            float h[8];
            h[0] = acc[i][0] + bb0.x; h[1] = acc[i][1] + bb0.y;
            h[2] = acc[i][2] + bb0.z; h[3] = acc[i][3] + bb0.w;
            h[4] = acc[i][4] + bb1.x; h[5] = acc[i][5] + bb1.y;
            h[6] = acc[i][6] + bb1.z; h[7] = acc[i][7] + bb1.w;
            *(float4*)(h1 + (size_t)row * D + c * 4)      = make_float4(h[0], h[1], h[2], h[3]);
            *(float4*)(h1 + (size_t)row * D + 64 + c * 4) = make_float4(h[4], h[5], h[6], h[7]);
            #pragma unroll
            for (int j = 0; j < 8; ++j) { cs[j] += h[j]; cq[j] += h[j] * h[j]; }
        }
    }

    __syncthreads();
    float* red = wsh;
    const int g = t >> 4;
    #pragma unroll
    for (int j = 0; j < 4; ++j) {
        red[g * 256 +       4 * c + j] = cs[j];
        red[g * 256 +  64 + 4 * c + j] = cs[4 + j];
        red[g * 256 + 128 + 4 * c + j] = cq[j];
        red[g * 256 + 192 + 4 * c + j] = cq[4 + j];
    }
    __syncthreads();
    float v = 0.f;
    #pragma unroll
    for (int g2 = 0; g2 < 16; ++g2) v += red[g2 * 256 + t];
    atomicAdd(stats + t, v);
}

__global__ void k_bn_finalize(float* __restrict__ stats,
                              const float* __restrict__ gamma,
                              const float* __restrict__ beta,
                              int N) {
    const int c = threadIdx.x;
    const float invN = 1.0f / (float)N;
    const float sum = stats[c];
    const float sq  = stats[D + c];
    const float mu  = sum * invN;
    const float var = sq * invN - mu * mu;
    const float sc  = gamma[c] * rsqrtf(var + 1e-5f);
    const float sh  = beta[c] - mu * sc;
    stats[c]     = sc;
    stats[D + c] = sh;
}

__global__ __launch_bounds__(256) void k_out(const float* __restrict__ h1,
                                             const float* __restrict__ agg_e,
                                             const float* __restrict__ stats,
                                             const float* __restrict__ W2,
                                             const float* __restrict__ b2,
                                             const float* __restrict__ We,
                                             const float* __restrict__ be,
                                             const int* __restrict__ row_ptr,
                                             float* __restrict__ out,
                                             int N) {
    __shared__ float xs[TR * 132];
    __shared__ float wsh[BK * 128];
    const int t = threadIdx.x;
    const int row0 = blockIdx.x * TR;
    const int rg = (t >> 4) * 4;
    const int c  = t & 15;

    float acc[4][8];
    #pragma unroll
    for (int i = 0; i < 4; ++i)
        #pragma unroll
        for (int j = 0; j < 8; ++j) acc[i][j] = 0.f;

    // ---- phase A: relu(bn(h1)) @ W2 ----
    for (int i = t; i < TR * 32; i += 256) {
        const int r = i >> 5, c4 = i & 31;
        const int row = row0 + r;
        float4 v = make_float4(0.f, 0.f, 0.f, 0.f);
        if (row < N) {
            const float4 h  = *(const float4*)(h1 + (size_t)row * D + c4 * 4);
            const float4 sc = *(const float4*)(stats + c4 * 4);
            const float4 sh = *(const float4*)(stats + 128 + c4 * 4);
            v.x = fmaxf(h.x * sc.x + sh.x, 0.f);
            v.y = fmaxf(h.y * sc.y + sh.y, 0.f);
            v.z = fmaxf(h.z * sc.z + sh.z, 0.f);
            v.w = fmaxf(h.w * sc.w + sh.w, 0.f);
        }
        *(float4*)(xs + r * 132 + c4 * 4) = v;
    }
    for (int kc = 0; kc < D; kc += BK) {
        __syncthreads();
        #pragma unroll
        for (int i = 0; i < 4; ++i) {
            const int slot = i * 256 + t;
            const int k = slot >> 5, ch = slot & 31;
            *(float4*)(wsh + k * 128 + ch * 4) =
                *(const float4*)(W2 + (kc + k) * D + ch * 4);
        }
        __syncthreads();
        #pragma unroll 8
        for (int k = 0; k < BK; ++k) {
            const float4 w0 = *(const float4*)(wsh + k * 128 + c * 4);
            const float4 w1 = *(const float4*)(wsh + k * 128 + 64 + c * 4);
            const float x0 = xs[(rg + 0) * 132 + kc + k];
            const float x1 = xs[(rg + 1) * 132 + kc + k];
            const float x2 = xs[(rg + 2) * 132 + kc + k];
            const float x3 = xs[(rg + 3) * 132 + kc + k];
            FMA_ROW(0, x0)
            FMA_ROW(1, x1)
            FMA_ROW(2, x2)
            FMA_ROW(3, x3)
        }
    }
    __syncthreads();

    // ---- phase B: agg_e @ We ----
    for (int i = t; i < TR * 32; i += 256) {
        const int r = i >> 5, c4 = i & 31;
        const int row = row0 + r;
        float4 v = make_float4(0.f, 0.f, 0.f, 0.f);
        if (row < N) v = *(const float4*)(agg_e + (size_t)row * D + c4 * 4);
        *(float4*)(xs + r * 132 + c4 * 4) = v;
    }
    for (int kc = 0; kc < D; kc += BK) {
        __syncthreads();
        #pragma unroll
        for (int i = 0; i < 4; ++i) {
            const int slot = i * 256 + t;
            const int k = slot >> 5, ch = slot & 31;
            *(float4*)(wsh + k * 128 + ch * 4) =
                *(const float4*)(We + (kc + k) * D + ch * 4);
        }
        __syncthreads();
        #pragma unroll 8
        for (int k = 0; k < BK; ++k) {
            const float4 w0 = *(const float4*)(wsh + k * 128 + c * 4);
            const float4 w1 = *(const float4*)(wsh + k * 128 + 64 + c * 4);
            const float x0 = xs[(rg + 0) * 132 + kc + k];
            const float x1 = xs[(rg + 1) * 132 + kc + k];
            const float x2 = xs[(rg + 2) * 132 + kc + k];
            const float x3 = xs[(rg + 3) * 132 + kc + k];
            FMA_ROW(0, x0)
            FMA_ROW(1, x1)
            FMA_ROW(2, x2)
            FMA_ROW(3, x3)
        }
    }

    const float4 b20 = *(const float4*)(b2 + c * 4);
    const float4 b21 = *(const float4*)(b2 + 64 + c * 4);
    const float4 be0 = *(const float4*)(be + c * 4);
    const float4 be1 = *(const float4*)(be + 64 + c * 4);
    #pragma unroll
    for (int i = 0; i < 4; ++i) {
        const int row = row0 + rg + i;
        if (row < N) {
            const float dg = (float)(row_ptr[row + 1] - row_ptr[row]);
            const float4 o0 = make_float4(acc[i][0] + b20.x + dg * be0.x,
                                          acc[i][1] + b20.y + dg * be0.y,
                                          acc[i][2] + b20.z + dg * be0.z,
                                          acc[i][3] + b20.w + dg * be0.w);
            const float4 o1 = make_float4(acc[i][4] + b21.x + dg * be1.x,
                                          acc[i][5] + b21.y + dg * be1.y,
                                          acc[i][6] + b21.z + dg * be1.z,
                                          acc[i][7] + b21.w + dg * be1.w);
            *(float4*)(out + (size_t)row * D + c * 4)      = o0;
            *(float4*)(out + (size_t)row * D + 64 + c * 4) = o1;
        }
    }
}

extern "C" void kernel_launch(void* const* d_in, const int* in_sizes, int n_in,
                              void* d_out, int out_size, void* d_ws, size_t ws_size,
                              hipStream_t stream) {
    const float* nfeat = (const float*)d_in[0];
    const float* efeat = (const float*)d_in[1];
    const int*   src   = (const int*)d_in[2];
    const int*   dst   = (const int*)d_in[3];
    const float* W1    = (const float*)d_in[4];
    const float* b1    = (const float*)d_in[5];
    const float* gamma = (const float*)d_in[6];
    const float* beta  = (const float*)d_in[7];
    const float* W2    = (const float*)d_in[8];
    const float* b2    = (const float*)d_in[9];
    const float* We    = (const float*)d_in[10];
    const float* be    = (const float*)d_in[11];
    float* out = (float*)d_out;

    const int N = in_sizes[0] / D;
    const int E = in_sizes[2];

    // workspace layout (h1 aliases xbuf: k_h1 stages its rows before writing them)
    float* ws      = (float*)d_ws;
    float* xbuf    = ws;                         // N*D
    float* h1      = xbuf;                       // aliased
    float* agg_e   = ws + (size_t)N * D;         // N*D
    float* stats   = ws + (size_t)2 * N * D;     // 256
    int*   row_ptr = (int*)(stats + 256);        // N+16
    int*   cursor  = row_ptr + (N + 16);         // N+16
    int*   cnt     = cursor + (N + 16);          // N+16
    int*   bsum    = cnt + (N + 16);             // 64
    int2*  epair   = (int2*)(bsum + 64);         // E int2

    const int ebl4 = (E / 4 + 255) / 256;
    const int scb  = (N + 1023) / 1024;

    k_zero<<<(N + 255) / 256, 256, 0, stream>>>(cnt, stats, N);
    k_hist<<<ebl4, 256, 0, stream>>>(dst, cnt, E);
    k_scan1<<<scb, 256, 0, stream>>>(cnt, row_ptr, bsum, N);
    k_scan2<<<1, 256, 0, stream>>>(bsum, scb);
    k_scan3<<<scb, 256, 0, stream>>>(row_ptr, cursor, bsum, N, E);
    k_scatter<<<ebl4, 256, 0, stream>>>(src, dst, cursor, epair, E);

    k_gather<<<(N + 3) / 4, 256, 0, stream>>>(nfeat, efeat, row_ptr, epair,
                                              xbuf, agg_e, N);

    const int nb = (N + TR - 1) / TR;
    k_h1<<<nb, 256, 0, stream>>>(xbuf, W1, b1, h1, stats, N);
    k_bn_finalize<<<1, 128, 0, stream>>>(stats, gamma, beta, N);
    k_out<<<nb, 256, 0, stream>>>(h1, agg_e, stats, W2, b2, We, be, row_ptr, out, N);
}

// Round 4
// 287.258 us; speedup vs baseline: 9.2722x; 1.1618x over previous
//
#include <hip/hip_runtime.h>

#define D 128

typedef __attribute__((ext_vector_type(8))) short bf16x8;   // 8 bf16 = 4 VGPR
typedef __attribute__((ext_vector_type(4))) float f32x4;    // MFMA C/D

static __device__ __forceinline__ float4 f4add(float4 a, float4 b) {
    return make_float4(a.x + b.x, a.y + b.y, a.z + b.z, a.w + b.w);
}
static __device__ __forceinline__ short f2bf(float f) {  // RNE bf16 bits
    union { float f; unsigned u; } v; v.f = f;
    const unsigned r = v.u + 0x7FFFu + ((v.u >> 16) & 1u);
    return (short)(r >> 16);
}
static __device__ __forceinline__ float bf2f(short s) {
    union { unsigned u; float f; } v;
    v.u = ((unsigned)(unsigned short)s) << 16;
    return v.f;
}

// ================= zero scratch =================
__global__ void k_zero(int* __restrict__ cnt, float* __restrict__ stats, int N) {
    const int i = blockIdx.x * 256 + threadIdx.x;
    if (i < N) cnt[i] = 0;
    if (i < 256) stats[i] = 0.f;
}

// ========== weight convert + transpose: Wt[n][k] = bf16(W[k][n]) ==========
__global__ void k_wt(const float* __restrict__ W1, const float* __restrict__ W2,
                     const float* __restrict__ We, short* __restrict__ Wt1,
                     short* __restrict__ Wt2, short* __restrict__ Wte) {
    const int i = blockIdx.x * 256 + threadIdx.x;  // 3 * 16384 total
    const int m = i >> 14;
    const int idx = i & 16383;
    const int k = idx >> 7, n = idx & 127;
    const float* W = (m == 0) ? W1 : (m == 1) ? W2 : We;
    short* Wt = (m == 0) ? Wt1 : (m == 1) ? Wt2 : Wte;
    Wt[n * 128 + k] = f2bf(W[k * 128 + n]);
}

// ================= CSR build =================
__global__ void k_hist(const int* __restrict__ dst, int* __restrict__ cnt, int E) {
    const int base = (blockIdx.x * 256 + threadIdx.x) * 4;
    if (base + 3 < E) {
        const int4 d4 = *(const int4*)(dst + base);
        atomicAdd(&cnt[d4.x], 1);
        atomicAdd(&cnt[d4.y], 1);
        atomicAdd(&cnt[d4.z], 1);
        atomicAdd(&cnt[d4.w], 1);
    } else {
        for (int e = base; e < E; ++e) atomicAdd(&cnt[dst[e]], 1);
    }
}

__global__ __launch_bounds__(256) void k_scan1(const int* __restrict__ cnt,
                                               int* __restrict__ row_ptr,
                                               int* __restrict__ bsum,
                                               float* __restrict__ degf, int N) {
    __shared__ int sh[256];
    const int t = threadIdx.x;
    const int base = blockIdx.x * 1024 + t * 4;
    int4 v = make_int4(0, 0, 0, 0);
    if (base + 3 < N) v = *(const int4*)(cnt + base);
    else {
        if (base     < N) v.x = cnt[base];
        if (base + 1 < N) v.y = cnt[base + 1];
        if (base + 2 < N) v.z = cnt[base + 2];
        if (base + 3 < N) v.w = cnt[base + 3];
    }
    if (base     < N) degf[base]     = (float)v.x;
    if (base + 1 < N) degf[base + 1] = (float)v.y;
    if (base + 2 < N) degf[base + 2] = (float)v.z;
    if (base + 3 < N) degf[base + 3] = (float)v.w;
    const int s = v.x + v.y + v.z + v.w;
    sh[t] = s;
    __syncthreads();
    for (int off = 1; off < 256; off <<= 1) {
        int tmp = (t >= off) ? sh[t - off] : 0;
        __syncthreads();
        sh[t] += tmp;
        __syncthreads();
    }
    const int p = sh[t] - s;
    if (base     < N) row_ptr[base]     = p;
    if (base + 1 < N) row_ptr[base + 1] = p + v.x;
    if (base + 2 < N) row_ptr[base + 2] = p + v.x + v.y;
    if (base + 3 < N) row_ptr[base + 3] = p + v.x + v.y + v.z;
    if (t == 255) bsum[blockIdx.x] = sh[255];
}

__global__ __launch_bounds__(256) void k_scan2(int* __restrict__ bsum, int nb) {
    __shared__ int sh[256];
    const int t = threadIdx.x;
    const int v = (t < nb) ? bsum[t] : 0;
    sh[t] = v;
    __syncthreads();
    for (int off = 1; off < 256; off <<= 1) {
        int tmp = (t >= off) ? sh[t - off] : 0;
        __syncthreads();
        sh[t] += tmp;
        __syncthreads();
    }
    if (t < nb) bsum[t] = sh[t] - v;
}

__global__ __launch_bounds__(256) void k_scan3(int* __restrict__ row_ptr,
                                               int* __restrict__ cursor,
                                               const int* __restrict__ bsum,
                                               int N, int E) {
    const int t = threadIdx.x;
    const int base = blockIdx.x * 1024 + t * 4;
    const int off = bsum[blockIdx.x];
    #pragma unroll
    for (int j = 0; j < 4; ++j) {
        const int i = base + j;
        if (i < N) {
            const int r = row_ptr[i] + off;
            row_ptr[i] = r;
            cursor[i] = r;
        }
    }
    if (blockIdx.x == 0 && t == 0) row_ptr[N] = E;
}

__global__ void k_scatter(const int* __restrict__ src, const int* __restrict__ dst,
                          int* __restrict__ cursor,
                          int2* __restrict__ epair, int E) {
    const int base = (blockIdx.x * 256 + threadIdx.x) * 4;
    if (base + 3 < E) {
        const int4 d4 = *(const int4*)(dst + base);
        const int4 s4 = *(const int4*)(src + base);
        int p;
        p = atomicAdd(&cursor[d4.x], 1); epair[p] = make_int2(base + 0, s4.x);
        p = atomicAdd(&cursor[d4.y], 1); epair[p] = make_int2(base + 1, s4.y);
        p = atomicAdd(&cursor[d4.z], 1); epair[p] = make_int2(base + 2, s4.z);
        p = atomicAdd(&cursor[d4.w], 1); epair[p] = make_int2(base + 3, s4.w);
    } else {
        for (int e = base; e < E; ++e) {
            const int p = atomicAdd(&cursor[dst[e]], 1);
            epair[p] = make_int2(e, src[e]);
        }
    }
}

// ===== gather: one wave per node; writes bf16 xbuf = nfeat+agg_n, agg_e =====
__global__ __launch_bounds__(256) void k_gather(const float* __restrict__ nfeat,
                                                const float* __restrict__ efeat,
                                                const int* __restrict__ row_ptr,
                                                const int2* __restrict__ epair,
                                                short* __restrict__ xbuf,
                                                short* __restrict__ agg_e,
                                                int N) {
    const int t = threadIdx.x;
    const int lane = t & 63;
    const int h = lane >> 5;
    const int c = lane & 31;
    const int node = blockIdx.x * 4 + (t >> 6);
    if (node >= N) return;

    const int start = row_ptr[node];
    const int end   = row_ptr[node + 1];

    float4 an = make_float4(0.f, 0.f, 0.f, 0.f);
    float4 ae = make_float4(0.f, 0.f, 0.f, 0.f);
    for (int e = start + h; e < end; e += 2) {
        const int2 p = epair[e];
        const float4 ev = *(const float4*)(efeat + (size_t)p.x * D + c * 4);
        const float4 nv = *(const float4*)(nfeat + (size_t)p.y * D + c * 4);
        ae = f4add(ae, ev);
        an = f4add(an, nv);
    }
    float4 an_t, ae_t;
    an_t.x = an.x + __shfl_xor(an.x, 32);
    an_t.y = an.y + __shfl_xor(an.y, 32);
    an_t.z = an.z + __shfl_xor(an.z, 32);
    an_t.w = an.w + __shfl_xor(an.w, 32);
    ae_t.x = ae.x + __shfl_xor(ae.x, 32);
    ae_t.y = ae.y + __shfl_xor(ae.y, 32);
    ae_t.z = ae.z + __shfl_xor(ae.z, 32);
    ae_t.w = ae.w + __shfl_xor(ae.w, 32);

    if (h == 0) {
        const float4 self = *(const float4*)(nfeat + (size_t)node * D + c * 4);
        const float4 xv = f4add(self, an_t);
        short4 xs4, es4;
        xs4.x = f2bf(xv.x);   xs4.y = f2bf(xv.y);
        xs4.z = f2bf(xv.z);   xs4.w = f2bf(xv.w);
        es4.x = f2bf(ae_t.x); es4.y = f2bf(ae_t.y);
        es4.z = f2bf(ae_t.z); es4.w = f2bf(ae_t.w);
        *(short4*)(xbuf  + (size_t)node * D + c * 4) = xs4;
        *(short4*)(agg_e + (size_t)node * D + c * 4) = es4;
    }
}

// ======= k_h1: h1 = xbuf @ W1 + b1 (bf16 MFMA), + BN stats atomics =======
// 64 rows/block, 4 waves; wave w owns cols [w*32, w*32+32)
// NOTE: xbuf and h1 alias (reads complete before epilogue writes) — no restrict
__global__ __launch_bounds__(256) void k_h1(const short* xbuf,
                                            const short* __restrict__ Wt1,
                                            const float* __restrict__ b1,
                                            short* h1,
                                            float* __restrict__ stats, int N) {
    const int t = threadIdx.x;
    const int lane = t & 63;
    const int w = t >> 6;
    const int l15 = lane & 15;
    const int kg = lane >> 4;
    const int row0 = blockIdx.x * 64;

    bf16x8 bfr[4][2];
    #pragma unroll
    for (int kt = 0; kt < 4; ++kt)
        #pragma unroll
        for (int cf = 0; cf < 2; ++cf)
            bfr[kt][cf] = *(const bf16x8*)(Wt1 + (w * 32 + cf * 16 + l15) * D +
                                           kt * 32 + kg * 8);

    f32x4 acc[4][2];
    #pragma unroll
    for (int rt = 0; rt < 4; ++rt) {
        acc[rt][0] = (f32x4)0.f;
        acc[rt][1] = (f32x4)0.f;
    }

    #pragma unroll
    for (int rt = 0; rt < 4; ++rt) {
        const int row = row0 + rt * 16 + l15;
        bf16x8 a0 = (bf16x8)(short)0, a1 = a0, a2 = a0, a3 = a0;
        if (row < N) {
            const short* xp = xbuf + (size_t)row * D + kg * 8;
            a0 = *(const bf16x8*)(xp);
            a1 = *(const bf16x8*)(xp + 32);
            a2 = *(const bf16x8*)(xp + 64);
            a3 = *(const bf16x8*)(xp + 96);
        }
        acc[rt][0] = __builtin_amdgcn_mfma_f32_16x16x32_bf16(a0, bfr[0][0], acc[rt][0], 0, 0, 0);
        acc[rt][1] = __builtin_amdgcn_mfma_f32_16x16x32_bf16(a0, bfr[0][1], acc[rt][1], 0, 0, 0);
        acc[rt][0] = __builtin_amdgcn_mfma_f32_16x16x32_bf16(a1, bfr[1][0], acc[rt][0], 0, 0, 0);
        acc[rt][1] = __builtin_amdgcn_mfma_f32_16x16x32_bf16(a1, bfr[1][1], acc[rt][1], 0, 0, 0);
        acc[rt][0] = __builtin_amdgcn_mfma_f32_16x16x32_bf16(a2, bfr[2][0], acc[rt][0], 0, 0, 0);
        acc[rt][1] = __builtin_amdgcn_mfma_f32_16x16x32_bf16(a2, bfr[2][1], acc[rt][1], 0, 0, 0);
        acc[rt][0] = __builtin_amdgcn_mfma_f32_16x16x32_bf16(a3, bfr[3][0], acc[rt][0], 0, 0, 0);
        acc[rt][1] = __builtin_amdgcn_mfma_f32_16x16x32_bf16(a3, bfr[3][1], acc[rt][1], 0, 0, 0);
    }

    const float bias0 = b1[w * 32 + l15];
    const float bias1 = b1[w * 32 + 16 + l15];
    float cs0 = 0.f, cq0 = 0.f, cs1 = 0.f, cq1 = 0.f;
    #pragma unroll
    for (int rt = 0; rt < 4; ++rt) {
        #pragma unroll
        for (int j = 0; j < 4; ++j) {
            const int row = row0 + rt * 16 + kg * 4 + j;
            if (row < N) {
                const float h0 = acc[rt][0][j] + bias0;
                const float h1v = acc[rt][1][j] + bias1;
                h1[(size_t)row * D + w * 32 + l15]      = f2bf(h0);
                h1[(size_t)row * D + w * 32 + 16 + l15] = f2bf(h1v);
                cs0 += h0; cq0 += h0 * h0;
                cs1 += h1v; cq1 += h1v * h1v;
            }
        }
    }
    #pragma unroll
    for (int m = 16; m < 64; m <<= 1) {
        cs0 += __shfl_xor(cs0, m); cq0 += __shfl_xor(cq0, m);
        cs1 += __shfl_xor(cs1, m); cq1 += __shfl_xor(cq1, m);
    }
    if (lane < 16) {
        atomicAdd(stats + w * 32 + lane,            cs0);
        atomicAdd(stats + w * 32 + 16 + lane,       cs1);
        atomicAdd(stats + 128 + w * 32 + lane,      cq0);
        atomicAdd(stats + 128 + w * 32 + 16 + lane, cq1);
    }
}

// ==== k_out: out = relu(bn(h1))@W2 + agg_e@We + b2 + deg*be (bf16 MFMA) ====
__global__ __launch_bounds__(256) void k_out(const short* __restrict__ h1,
                                             const short* __restrict__ agg_e,
                                             const short* __restrict__ Wt2,
                                             const short* __restrict__ Wte,
                                             const float* __restrict__ stats,
                                             const float* __restrict__ gamma,
                                             const float* __restrict__ beta,
                                             const float* __restrict__ b2,
                                             const float* __restrict__ be,
                                             const float* __restrict__ degf,
                                             float* __restrict__ out, int N) {
    __shared__ float scs[128], shs[128];
    const int t = threadIdx.x;
    if (t < 128) {
        const float invN = 1.0f / (float)N;
        const float mu = stats[t] * invN;
        const float var = stats[128 + t] * invN - mu * mu;
        const float sc = gamma[t] * rsqrtf(var + 1e-5f);
        scs[t] = sc;
        shs[t] = beta[t] - mu * sc;
    }
    __syncthreads();

    const int lane = t & 63;
    const int w = t >> 6;
    const int l15 = lane & 15;
    const int kg = lane >> 4;
    const int row0 = blockIdx.x * 64;

    f32x4 acc[4][2];
    #pragma unroll
    for (int rt = 0; rt < 4; ++rt) {
        acc[rt][0] = (f32x4)0.f;
        acc[rt][1] = (f32x4)0.f;
    }

    bf16x8 bfr[4][2];

    // ---- phase A: relu(bn(h1)) @ W2 ----
    #pragma unroll
    for (int kt = 0; kt < 4; ++kt)
        #pragma unroll
        for (int cf = 0; cf < 2; ++cf)
            bfr[kt][cf] = *(const bf16x8*)(Wt2 + (w * 32 + cf * 16 + l15) * D +
                                           kt * 32 + kg * 8);

    #pragma unroll
    for (int rt = 0; rt < 4; ++rt) {
        const int row = row0 + rt * 16 + l15;
        #pragma unroll
        for (int kt = 0; kt < 4; ++kt) {
            bf16x8 raw = (bf16x8)(short)0;
            if (row < N)
                raw = *(const bf16x8*)(h1 + (size_t)row * D + kt * 32 + kg * 8);
            const int k0 = kt * 32 + kg * 8;
            const float4 sa = *(const float4*)(scs + k0);
            const float4 sb = *(const float4*)(scs + k0 + 4);
            const float4 ha = *(const float4*)(shs + k0);
            const float4 hb = *(const float4*)(shs + k0 + 4);
            bf16x8 afr;
            afr[0] = f2bf(fmaxf(bf2f(raw[0]) * sa.x + ha.x, 0.f));
            afr[1] = f2bf(fmaxf(bf2f(raw[1]) * sa.y + ha.y, 0.f));
            afr[2] = f2bf(fmaxf(bf2f(raw[2]) * sa.z + ha.z, 0.f));
            afr[3] = f2bf(fmaxf(bf2f(raw[3]) * sa.w + ha.w, 0.f));
            afr[4] = f2bf(fmaxf(bf2f(raw[4]) * sb.x + hb.x, 0.f));
            afr[5] = f2bf(fmaxf(bf2f(raw[5]) * sb.y + hb.y, 0.f));
            afr[6] = f2bf(fmaxf(bf2f(raw[6]) * sb.z + hb.z, 0.f));
            afr[7] = f2bf(fmaxf(bf2f(raw[7]) * sb.w + hb.w, 0.f));
            acc[rt][0] = __builtin_amdgcn_mfma_f32_16x16x32_bf16(afr, bfr[kt][0], acc[rt][0], 0, 0, 0);
            acc[rt][1] = __builtin_amdgcn_mfma_f32_16x16x32_bf16(afr, bfr[kt][1], acc[rt][1], 0, 0, 0);
        }
    }

    // ---- phase B: agg_e @ We ----
    #pragma unroll
    for (int kt = 0; kt < 4; ++kt)
        #pragma unroll
        for (int cf = 0; cf < 2; ++cf)
            bfr[kt][cf] = *(const bf16x8*)(Wte + (w * 32 + cf * 16 + l15) * D +
                                           kt * 32 + kg * 8);

    #pragma unroll
    for (int rt = 0; rt < 4; ++rt) {
        const int row = row0 + rt * 16 + l15;
        bf16x8 a0 = (bf16x8)(short)0, a1 = a0, a2 = a0, a3 = a0;
        if (row < N) {
            const short* ap = agg_e + (size_t)row * D + kg * 8;
            a0 = *(const bf16x8*)(ap);
            a1 = *(const bf16x8*)(ap + 32);
            a2 = *(const bf16x8*)(ap + 64);
            a3 = *(const bf16x8*)(ap + 96);
        }
        acc[rt][0] = __builtin_amdgcn_mfma_f32_16x16x32_bf16(a0, bfr[0][0], acc[rt][0], 0, 0, 0);
        acc[rt][1] = __builtin_amdgcn_mfma_f32_16x16x32_bf16(a0, bfr[0][1], acc[rt][1], 0, 0, 0);
        acc[rt][0] = __builtin_amdgcn_mfma_f32_16x16x32_bf16(a1, bfr[1][0], acc[rt][0], 0, 0, 0);
        acc[rt][1] = __builtin_amdgcn_mfma_f32_16x16x32_bf16(a1, bfr[1][1], acc[rt][1], 0, 0, 0);
        acc[rt][0] = __builtin_amdgcn_mfma_f32_16x16x32_bf16(a2, bfr[2][0], acc[rt][0], 0, 0, 0);
        acc[rt][1] = __builtin_amdgcn_mfma_f32_16x16x32_bf16(a2, bfr[2][1], acc[rt][1], 0, 0, 0);
        acc[rt][0] = __builtin_amdgcn_mfma_f32_16x16x32_bf16(a3, bfr[3][0], acc[rt][0], 0, 0, 0);
        acc[rt][1] = __builtin_amdgcn_mfma_f32_16x16x32_bf16(a3, bfr[3][1], acc[rt][1], 0, 0, 0);
    }

    // ---- epilogue ----
    const float b2_0 = b2[w * 32 + l15];
    const float b2_1 = b2[w * 32 + 16 + l15];
    const float be_0 = be[w * 32 + l15];
    const float be_1 = be[w * 32 + 16 + l15];
    #pragma unroll
    for (int rt = 0; rt < 4; ++rt) {
        const int rbase = row0 + rt * 16 + kg * 4;
        float dgv[4];
        if (rbase + 3 < N) {
            *(float4*)dgv = *(const float4*)(degf + rbase);
        } else {
            #pragma unroll
            for (int j = 0; j < 4; ++j)
                dgv[j] = (rbase + j < N) ? degf[rbase + j] : 0.f;
        }
        #pragma unroll
        for (int j = 0; j < 4; ++j) {
            const int row = rbase + j;
            if (row < N) {
                out[(size_t)row * D + w * 32 + l15] =
                    acc[rt][0][j] + b2_0 + dgv[j] * be_0;
                out[(size_t)row * D + w * 32 + 16 + l15] =
                    acc[rt][1][j] + b2_1 + dgv[j] * be_1;
            }
        }
    }
}

extern "C" void kernel_launch(void* const* d_in, const int* in_sizes, int n_in,
                              void* d_out, int out_size, void* d_ws, size_t ws_size,
                              hipStream_t stream) {
    const float* nfeat = (const float*)d_in[0];
    const float* efeat = (const float*)d_in[1];
    const int*   src   = (const int*)d_in[2];
    const int*   dst   = (const int*)d_in[3];
    const float* W1    = (const float*)d_in[4];
    const float* b1    = (const float*)d_in[5];
    const float* gamma = (const float*)d_in[6];
    const float* beta  = (const float*)d_in[7];
    const float* W2    = (const float*)d_in[8];
    const float* b2    = (const float*)d_in[9];
    const float* We    = (const float*)d_in[10];
    const float* be    = (const float*)d_in[11];
    float* out = (float*)d_out;

    const int N = in_sizes[0] / D;
    const int E = in_sizes[2];
    const size_t ND = (size_t)N * D;

    // workspace layout (all 16B-aligned by construction; h1 aliases xbuf)
    short* xbuf   = (short*)d_ws;                // N*D bf16
    short* h1     = xbuf;                        // aliased
    short* agg_e  = xbuf + ND;                   // N*D bf16
    short* Wt1    = agg_e + ND;                  // 16384
    short* Wt2    = Wt1 + 16384;
    short* Wte    = Wt2 + 16384;
    float* stats  = (float*)(Wte + 16384);       // 256
    float* degf   = stats + 256;                 // N
    int*   row_ptr= (int*)(degf + N);            // N+16
    int*   cursor = row_ptr + (N + 16);          // N+16
    int*   cnt    = cursor + (N + 16);           // N+16
    int*   bsum   = cnt + (N + 16);              // 64
    int2*  epair  = (int2*)(bsum + 64);          // E

    const int ebl4 = (E / 4 + 255) / 256;
    const int scb  = (N + 1023) / 1024;
    const int nb   = (N + 63) / 64;

    k_zero<<<(N + 255) / 256, 256, 0, stream>>>(cnt, stats, N);
    k_wt<<<192, 256, 0, stream>>>(W1, W2, We, Wt1, Wt2, Wte);
    k_hist<<<ebl4, 256, 0, stream>>>(dst, cnt, E);
    k_scan1<<<scb, 256, 0, stream>>>(cnt, row_ptr, bsum, degf, N);
    k_scan2<<<1, 256, 0, stream>>>(bsum, scb);
    k_scan3<<<scb, 256, 0, stream>>>(row_ptr, cursor, bsum, N, E);
    k_scatter<<<ebl4, 256, 0, stream>>>(src, dst, cursor, epair, E);

    k_gather<<<(N + 3) / 4, 256, 0, stream>>>(nfeat, efeat, row_ptr, epair,
                                              xbuf, agg_e, N);

    k_h1<<<nb, 256, 0, stream>>>(xbuf, Wt1, b1, h1, stats, N);
    k_out<<<nb, 256, 0, stream>>>(h1, agg_e, Wt2, Wte, stats, gamma, beta,
                                  b2, be, degf, out, N);
}